// Round 6
// baseline (125.120 us; speedup 1.0000x reference)
//
#include <hip/hip_runtime.h>
#include <math.h>

// Depthwise 5x5 Gaussian blur, sigma from device scalar.
// x: (16, 256, 64, 64) fp32, out same, zero pad 2. Separable.
//
// Barrier-free / LDS-free, ONE WAVE PER PLANE, ZERO read redundancy:
// lane l owns column-quad c4=l&15 and rows [g16, g16+16), g16=(l>>4)*16.
// 16 float4 nontemporal loads (exactly its own rows), horizontal 5-tap with
// __shfl column halos, then the 4 vertical-halo h-rows come from lanes +-16
// via __shfl of already-computed h values, vertical 5-tap, 16 nontemporal
// float4 stores. No __syncthreads anywhere.

constexpr int Hh = 64;
constexpr int Ww = 64;
constexpr int KS = 5;
constexpr int PADc = 2;

typedef float vf4 __attribute__((ext_vector_type(4)));  // clang-native for nt builtins

__global__ __launch_bounds__(256, 2) void gauss5(const float* __restrict__ x,
                                                 const float* __restrict__ sigma,
                                                 float* __restrict__ out) {
    const int t    = threadIdx.x;
    const int lane = t & 63;
    const int wid  = t >> 6;
    const size_t plane = (size_t)blockIdx.x * 4 + wid;

    const int c4  = lane & 15;            // column quad 0..15
    const int grp = lane >> 4;            // row group 0..3
    const int g16 = grp << 4;             // first row of strip

    // --- normalized 1-D Gaussian taps ---
    const float sg = sigma[0];
    const float c2 = -1.0f / (2.0f * sg * sg);
    float w[KS];
    float wsum = 0.0f;
#pragma unroll
    for (int i = 0; i < KS; ++i) {
        float d = (float)(i - PADc);
        w[i] = expf(d * d * c2);
        wsum += w[i];
    }
    const float winv = 1.0f / wsum;
#pragma unroll
    for (int i = 0; i < KS; ++i) w[i] *= winv;

    const vf4* __restrict__ x4 = (const vf4*)(x + plane * (Hh * Ww));
    vf4* __restrict__ o4       = (vf4*)(out + plane * (Hh * Ww));

    const int lm1 = lane - 1;             // col-halo shfl srcs (masked at edges)
    const int lp1 = lane + 1;
    const bool leftEdge  = (c4 == 0);
    const bool rightEdge = (c4 == 15);

    // --- load own 16 rows (nontemporal), horizontal conv into h[16] ---
    vf4 v[16];
#pragma unroll
    for (int i = 0; i < 16; ++i)
        v[i] = __builtin_nontemporal_load(&x4[(g16 + i) * 16 + c4]);

    vf4 h[16];
#pragma unroll
    for (int i = 0; i < 16; ++i) {
        vf4 a = v[i];
        float lz = __shfl(a.z, lm1, 64);
        float lw = __shfl(a.w, lm1, 64);
        float rx = __shfl(a.x, lp1, 64);
        float ry = __shfl(a.y, lp1, 64);
        lz = leftEdge  ? 0.f : lz;
        lw = leftEdge  ? 0.f : lw;
        rx = rightEdge ? 0.f : rx;
        ry = rightEdge ? 0.f : ry;
        h[i].x = w[0]*lz  + w[1]*lw  + w[2]*a.x + w[3]*a.y + w[4]*a.z;
        h[i].y = w[0]*lw  + w[1]*a.x + w[2]*a.y + w[3]*a.z + w[4]*a.w;
        h[i].z = w[0]*a.x + w[1]*a.y + w[2]*a.z + w[3]*a.w + w[4]*rx;
        h[i].w = w[0]*a.y + w[1]*a.z + w[2]*a.w + w[3]*rx  + w[4]*ry;
    }

    // --- vertical halo h-rows from neighbor lane groups (lane +-16) ---
    const int lup = (lane + 48) & 63;     // lane-16 (wraps; masked for grp==0)
    const int ldn = (lane + 16) & 63;     // lane+16 (wraps; masked for grp==3)
    vf4 ha, hb, hc, hd;
    ha.x = __shfl(h[14].x, lup, 64); ha.y = __shfl(h[14].y, lup, 64);
    ha.z = __shfl(h[14].z, lup, 64); ha.w = __shfl(h[14].w, lup, 64);
    hb.x = __shfl(h[15].x, lup, 64); hb.y = __shfl(h[15].y, lup, 64);
    hb.z = __shfl(h[15].z, lup, 64); hb.w = __shfl(h[15].w, lup, 64);
    hc.x = __shfl(h[0].x,  ldn, 64); hc.y = __shfl(h[0].y,  ldn, 64);
    hc.z = __shfl(h[0].z,  ldn, 64); hc.w = __shfl(h[0].w,  ldn, 64);
    hd.x = __shfl(h[1].x,  ldn, 64); hd.y = __shfl(h[1].y,  ldn, 64);
    hd.z = __shfl(h[1].z,  ldn, 64); hd.w = __shfl(h[1].w,  ldn, 64);
    if (grp == 0) { ha = 0.f; hb = 0.f; }
    if (grp == 3) { hc = 0.f; hd = 0.f; }

    // --- vertical conv + nontemporal store ---
    {   // r = 0
        vf4 a = w[0]*ha + w[1]*hb + w[2]*h[0] + w[3]*h[1] + w[4]*h[2];
        __builtin_nontemporal_store(a, &o4[(g16 + 0) * 16 + c4]);
    }
    {   // r = 1
        vf4 a = w[0]*hb + w[1]*h[0] + w[2]*h[1] + w[3]*h[2] + w[4]*h[3];
        __builtin_nontemporal_store(a, &o4[(g16 + 1) * 16 + c4]);
    }
#pragma unroll
    for (int r = 2; r <= 13; ++r) {
        vf4 a = w[0]*h[r-2] + w[1]*h[r-1] + w[2]*h[r] + w[3]*h[r+1] + w[4]*h[r+2];
        __builtin_nontemporal_store(a, &o4[(g16 + r) * 16 + c4]);
    }
    {   // r = 14
        vf4 a = w[0]*h[12] + w[1]*h[13] + w[2]*h[14] + w[3]*h[15] + w[4]*hc;
        __builtin_nontemporal_store(a, &o4[(g16 + 14) * 16 + c4]);
    }
    {   // r = 15
        vf4 a = w[0]*h[13] + w[1]*h[14] + w[2]*h[15] + w[3]*hc + w[4]*hd;
        __builtin_nontemporal_store(a, &o4[(g16 + 15) * 16 + c4]);
    }
}

extern "C" void kernel_launch(void* const* d_in, const int* in_sizes, int n_in,
                              void* d_out, int out_size, void* d_ws, size_t ws_size,
                              hipStream_t stream) {
    const float* x     = (const float*)d_in[0];
    const float* sigma = (const float*)d_in[1];
    float* out         = (float*)d_out;
    const int planes = in_sizes[0] / (Hh * Ww);  // 4096
    gauss5<<<planes / 4, 256, 0, stream>>>(x, sigma, out);  // 1 wave : 1 plane
}